// Round 3
// baseline (621.671 us; speedup 1.0000x reference)
//
#include <hip/hip_runtime.h>
#include <hip/hip_bf16.h>

#define B_N    64
#define K_LEN  2000
#define D_DIM  512
#define NEG_INF (-3.402823466e38f)
#define EPS_C  1e-6f
#define INV_SCALE (1.0f/22.62741699796952f)   // 1/sqrt(512)

// -------- kernel 1: fused q/v projection per (b,branch) --------
__global__ __launch_bounds__(256) void proj_kernel(
    const float* __restrict__ query,
    const float* __restrict__ Wq_m, const float* __restrict__ bq_m,
    const float* __restrict__ Wq_c, const float* __restrict__ bq_c,
    const float* __restrict__ Wk_m, const float* __restrict__ bk_m,
    const float* __restrict__ Wk_c, const float* __restrict__ bk_c,
    const float* __restrict__ r,
    float* __restrict__ v_all, float* __restrict__ c_all)
{
    const int b = blockIdx.x, br = blockIdx.y, t = threadIdx.x;
    const float* Wq = br ? Wq_c : Wq_m;
    const float* bq = br ? bq_c : bq_m;
    const float* Wk = br ? Wk_c : Wk_m;
    const float* bk = br ? bk_c : bk_m;
    __shared__ float qs[D_DIM];   // query vector
    __shared__ float qv[D_DIM];   // projected q
    __shared__ float red[256];
    for (int i = t; i < D_DIM; i += 256) qs[i] = query[(size_t)b*D_DIM + i];
    __syncthreads();
    // stage 1: column dot-products
    for (int a = t; a < D_DIM; a += 256) {
        float a0 = 0.f, a1 = 0.f, a2 = 0.f, a3 = 0.f;
        #pragma unroll 4
        for (int d = 0; d < D_DIM; d += 4) {
            a0 = fmaf(qs[d+0], Wq[(size_t)(d+0)*D_DIM + a], a0);
            a1 = fmaf(qs[d+1], Wq[(size_t)(d+1)*D_DIM + a], a1);
            a2 = fmaf(qs[d+2], Wq[(size_t)(d+2)*D_DIM + a], a2);
            a3 = fmaf(qs[d+3], Wq[(size_t)(d+3)*D_DIM + a], a3);
        }
        qv[a] = (a0 + a1) + (a2 + a3) + bq[a];
    }
    __syncthreads();
    // stage 2: row dot-products (coalesced float4 within row)
    for (int d = t; d < D_DIM; d += 256) {
        const float4* row = (const float4*)(Wk + (size_t)d*D_DIM);
        const float4* q4 = (const float4*)qv;
        float acc = 0.f;
        #pragma unroll 4
        for (int a4 = 0; a4 < D_DIM/4; ++a4) {
            float4 w = row[a4], q = q4[a4];
            acc = fmaf(w.x, q.x, acc); acc = fmaf(w.y, q.y, acc);
            acc = fmaf(w.z, q.z, acc); acc = fmaf(w.w, q.w, acc);
        }
        v_all[((size_t)b*2 + br)*D_DIM + d] = acc * INV_SCALE;
    }
    float part = 0.f;
    for (int a = t; a < D_DIM; a += 256) part = fmaf(qv[a], bk[a], part);
    red[t] = part; __syncthreads();
    for (int s = 128; s; s >>= 1) { if (t < s) red[t] += red[t + s]; __syncthreads(); }
    if (t == 0) c_all[b*2 + br] = red[0] * INV_SCALE + (br ? 0.f : r[0]);
}

// -------- kernel 2: energies, one pass over key, coalesced halves --------
__global__ __launch_bounds__(256) void energy_kernel(
    const float* __restrict__ key, const int* __restrict__ mask,
    const float* __restrict__ v_all, const float* __restrict__ c_all,
    float* __restrict__ e_mono, float* __restrict__ e_c)
{
    const int b = blockIdx.x;
    const int kb0 = blockIdx.y * 125;          // 16 chunks * 125 = 2000
    const int kend = kb0 + 125;
    const int lane = threadIdx.x & 63;
    const int wave = threadIdx.x >> 6;
    const float4* vm4 = (const float4*)(v_all + ((size_t)b*2 + 0)*D_DIM);
    const float4* vc4 = (const float4*)(v_all + ((size_t)b*2 + 1)*D_DIM);
    // lane-contiguous halves: lanes 0..63 cover float4 idx 0..63 then 64..127
    const float4 vmA = vm4[lane], vmB = vm4[64 + lane];
    const float4 vcA = vc4[lane], vcB = vc4[64 + lane];
    const float cm = c_all[b*2 + 0], cc = c_all[b*2 + 1];

    for (int k = kb0 + wave; k < kend; k += 8) {
        const int k2 = k + 4;
        const bool has2 = (k2 < kend);
        const float4* kr0 = (const float4*)(key + ((size_t)b*K_LEN + k)*D_DIM);
        const float4* kr1 = (const float4*)(key + ((size_t)b*K_LEN + (has2 ? k2 : k))*D_DIM);
        float4 a0 = kr0[lane], b0 = kr0[64 + lane];
        float4 a1 = kr1[lane], b1 = kr1[64 + lane];
        float dm0 = 0.f, dc0 = 0.f, dm1 = 0.f, dc1 = 0.f;
        dm0 = fmaf(a0.x, vmA.x, dm0); dm0 = fmaf(a0.y, vmA.y, dm0);
        dm0 = fmaf(a0.z, vmA.z, dm0); dm0 = fmaf(a0.w, vmA.w, dm0);
        dm0 = fmaf(b0.x, vmB.x, dm0); dm0 = fmaf(b0.y, vmB.y, dm0);
        dm0 = fmaf(b0.z, vmB.z, dm0); dm0 = fmaf(b0.w, vmB.w, dm0);
        dc0 = fmaf(a0.x, vcA.x, dc0); dc0 = fmaf(a0.y, vcA.y, dc0);
        dc0 = fmaf(a0.z, vcA.z, dc0); dc0 = fmaf(a0.w, vcA.w, dc0);
        dc0 = fmaf(b0.x, vcB.x, dc0); dc0 = fmaf(b0.y, vcB.y, dc0);
        dc0 = fmaf(b0.z, vcB.z, dc0); dc0 = fmaf(b0.w, vcB.w, dc0);
        dm1 = fmaf(a1.x, vmA.x, dm1); dm1 = fmaf(a1.y, vmA.y, dm1);
        dm1 = fmaf(a1.z, vmA.z, dm1); dm1 = fmaf(a1.w, vmA.w, dm1);
        dm1 = fmaf(b1.x, vmB.x, dm1); dm1 = fmaf(b1.y, vmB.y, dm1);
        dm1 = fmaf(b1.z, vmB.z, dm1); dm1 = fmaf(b1.w, vmB.w, dm1);
        dc1 = fmaf(a1.x, vcA.x, dc1); dc1 = fmaf(a1.y, vcA.y, dc1);
        dc1 = fmaf(a1.z, vcA.z, dc1); dc1 = fmaf(a1.w, vcA.w, dc1);
        dc1 = fmaf(b1.x, vcB.x, dc1); dc1 = fmaf(b1.y, vcB.y, dc1);
        dc1 = fmaf(b1.z, vcB.z, dc1); dc1 = fmaf(b1.w, vcB.w, dc1);
        #pragma unroll
        for (int off = 32; off; off >>= 1) {
            dm0 += __shfl_xor(dm0, off); dc0 += __shfl_xor(dc0, off);
            dm1 += __shfl_xor(dm1, off); dc1 += __shfl_xor(dc1, off);
        }
        if (lane == 0) {
            size_t gk = (size_t)b*K_LEN + k;
            bool mk = mask[gk] != 0;
            e_mono[gk] = mk ? dm0 + cm : NEG_INF;
            e_c[gk]    = mk ? dc0 + cc : NEG_INF;
            if (has2) {
                size_t gk2 = (size_t)b*K_LEN + k2;
                bool mk2 = mask[gk2] != 0;
                e_mono[gk2] = mk2 ? dm1 + cm : NEG_INF;
                e_c[gk2]    = mk2 ? dc1 + cc : NEG_INF;
            }
        }
    }
}

// -------- kernel 3: per-batch scans, 512 threads / 4 elems each --------
__global__ __launch_bounds__(512) void scan_kernel(
    const float* __restrict__ e_mono_g, const float* __restrict__ e_c_g,
    const float* __restrict__ noise, const float* __restrict__ aw_prev,
    float* __restrict__ alpha_out, float* __restrict__ beta_out)
{
    const int b = blockIdx.x, t = threadIdx.x;
    const int lane = t & 63, wv = t >> 6;         // 8 waves
    __shared__ float sal[2048];  // alpha
    __shared__ float sse[2048];  // e_c then sm_exp
    __shared__ float su[2048];   // alpha/denom
    __shared__ float wsA[8], wsB[8], wsM[8];

    const float* em = e_mono_g + (size_t)b*K_LEN;
    const float* ec = e_c_g   + (size_t)b*K_LEN;
    const float* nz = noise   + (size_t)b*K_LEN;
    const float* aw = aw_prev + (size_t)b*K_LEN;

    const int base = t*4;
    float p[4], lg[4];
    #pragma unroll
    for (int j = 0; j < 4; ++j) {
        const int k = base + j;
        float pv = 0.f, lv = 0.f, ecv = NEG_INF;
        if (k < K_LEN) {
            float e = em[k] + nz[k];             // NOISE_STD = 1
            pv = 1.f / (1.f + expf(-e));
            float om = fminf(fmaxf(1.f - pv, EPS_C), 1.f);
            lv = logf(om);
            ecv = ec[k];
        }
        p[j] = pv; lg[j] = lv; sse[k] = ecv;
    }

    // ---- scan 1: exclusive cumsum of log(1-p) ----
    float ex[4]; float run = 0.f;
    #pragma unroll
    for (int j = 0; j < 4; ++j) { ex[j] = run; run += lg[j]; }
    float incl = run;
    #pragma unroll
    for (int off = 1; off < 64; off <<= 1) {
        float v = __shfl_up(incl, off, 64);
        if (lane >= off) incl += v;
    }
    if (lane == 63) wsA[wv] = incl;
    __syncthreads();                                         // (1)
    float wpre = 0.f;
    #pragma unroll
    for (int w = 0; w < 8; ++w) if (w < wv) wpre += wsA[w];
    const float pre = wpre + incl - run;                     // thread-exclusive

    // cp + scan 2 input
    float cp[4], t2i[4]; float run2 = 0.f;
    #pragma unroll
    for (int j = 0; j < 4; ++j) {
        const int k = base + j;
        float c = expf(pre + ex[j]);
        cp[j] = c;
        float t2 = 0.f;
        if (k < K_LEN) t2 = aw[k] / fminf(fmaxf(c, EPS_C), 1.f);
        run2 += t2; t2i[j] = run2;                           // thread-inclusive
    }
    float incl2 = run2;
    #pragma unroll
    for (int off = 1; off < 64; off <<= 1) {
        float v = __shfl_up(incl2, off, 64);
        if (lane >= off) incl2 += v;
    }
    if (lane == 63) wsB[wv] = incl2;
    __syncthreads();                                         // (2)
    float wpre2 = 0.f;
    #pragma unroll
    for (int w = 0; w < 8; ++w) if (w < wv) wpre2 += wsB[w];
    const float pre2 = wpre2 + incl2 - run2;
    #pragma unroll
    for (int j = 0; j < 4; ++j) {
        const int k = base + j;
        float al = p[j] * cp[j] * (pre2 + t2i[j]);
        sal[k] = al;
        if (k < K_LEN) alpha_out[(size_t)b*K_LEN + k] = al;
    }
    __syncthreads();                                         // (3)

    // ---- max over e_c ----
    float mx = NEG_INF;
    for (int k = t; k < 2048; k += 512) mx = fmaxf(mx, sse[k]);
    #pragma unroll
    for (int off = 32; off; off >>= 1) mx = fmaxf(mx, __shfl_xor(mx, off));
    if (lane == 0) wsM[wv] = mx;
    __syncthreads();                                         // (4)
    mx = wsM[0];
    #pragma unroll
    for (int w = 1; w < 8; ++w) mx = fmaxf(mx, wsM[w]);

    for (int k = t; k < 2048; k += 512) {
        float se = 0.f;
        if (k < K_LEN) se = fmaxf(expf(sse[k] - mx), 1e-5f);
        sse[k] = se;
    }
    __syncthreads();                                         // (5)
    // denom = moving_sum(sm_exp, back=7, fwd=0); u = alpha/denom
    for (int k = t; k < 2048; k += 512) {
        float u = 0.f;
        if (k < K_LEN) {
            float den = 0.f;
            int j0 = (k > 7) ? (k - 7) : 0;
            for (int j = j0; j <= k; ++j) den += sse[j];
            u = sal[k] / den;                                // SHARP = 1
        }
        su[k] = u;
    }
    __syncthreads();                                         // (6)
    // beta = sm_exp * moving_sum(u, back=0, fwd=7)
    for (int k = t; k < K_LEN; k += 512) {
        float s2 = 0.f;
        #pragma unroll
        for (int j = 0; j < 8; ++j) s2 += su[k + j];
        beta_out[(size_t)b*K_LEN + k] = sse[k] * s2;
    }
}

// -------- kernel 4: cv, one pass over value, atomic accumulate --------
__global__ __launch_bounds__(256) void cv_part_kernel(
    const float* __restrict__ value, const float* __restrict__ beta,
    float* __restrict__ cv)
{
    const int b = blockIdx.x, s = blockIdx.y, t = threadIdx.x;
    const int f4 = t & 127, rp = t >> 7;
    const int k0 = s * 100;
    __shared__ float bs[100];
    __shared__ float4 comb[128];
    if (t < 100) bs[t] = beta[(size_t)b*K_LEN + k0 + t];
    __syncthreads();
    float4 acc0 = {0.f, 0.f, 0.f, 0.f}, acc1 = {0.f, 0.f, 0.f, 0.f};
    // rows k0+rp, k0+rp+2 in flight (2 independent loads per wave iter)
    for (int k = k0 + rp; k < k0 + 100; k += 4) {
        float4 v0 = ((const float4*)(value + ((size_t)b*K_LEN + k)*D_DIM))[f4];
        float4 v1 = ((const float4*)(value + ((size_t)b*K_LEN + k + 2)*D_DIM))[f4];
        float b0 = bs[k - k0], b1 = bs[k - k0 + 2];
        acc0.x = fmaf(b0, v0.x, acc0.x); acc0.y = fmaf(b0, v0.y, acc0.y);
        acc0.z = fmaf(b0, v0.z, acc0.z); acc0.w = fmaf(b0, v0.w, acc0.w);
        acc1.x = fmaf(b1, v1.x, acc1.x); acc1.y = fmaf(b1, v1.y, acc1.y);
        acc1.z = fmaf(b1, v1.z, acc1.z); acc1.w = fmaf(b1, v1.w, acc1.w);
    }
    acc0.x += acc1.x; acc0.y += acc1.y; acc0.z += acc1.z; acc0.w += acc1.w;
    if (rp) comb[f4] = acc0;
    __syncthreads();
    if (!rp) {
        float4 o = comb[f4];
        float* dst = cv + (size_t)b*D_DIM + f4*4;
        atomicAdd(dst + 0, acc0.x + o.x);
        atomicAdd(dst + 1, acc0.y + o.y);
        atomicAdd(dst + 2, acc0.z + o.z);
        atomicAdd(dst + 3, acc0.w + o.w);
    }
}

extern "C" void kernel_launch(void* const* d_in, const int* in_sizes, int n_in,
                              void* d_out, int out_size, void* d_ws, size_t ws_size,
                              hipStream_t stream) {
    const float* key     = (const float*)d_in[0];
    const float* value   = (const float*)d_in[1];
    const float* query   = (const float*)d_in[2];
    const int*   mask    = (const int*)d_in[3];
    const float* aw_prev = (const float*)d_in[4];
    const float* noise   = (const float*)d_in[5];
    const float* Wk_m    = (const float*)d_in[6];
    const float* bk_m    = (const float*)d_in[7];
    const float* Wq_m    = (const float*)d_in[8];
    const float* bq_m    = (const float*)d_in[9];
    const float* r       = (const float*)d_in[10];
    const float* Wk_c    = (const float*)d_in[11];
    const float* bk_c    = (const float*)d_in[12];
    const float* Wq_c    = (const float*)d_in[13];
    const float* bq_c    = (const float*)d_in[14];

    float* out   = (float*)d_out;
    float* cv    = out;                       // [64,1,512] = 32768
    float* alpha = out + (size_t)B_N*D_DIM;   // [64,2000]  = 128000

    float* ws      = (float*)d_ws;
    float* e_mono  = ws;                  // 128000
    float* e_c     = ws + 128000;         // 128000
    float* beta    = ws + 256000;         // 128000
    float* v_all   = ws + 384000;         // 65536
    float* c_all   = ws + 449536;         // 128

    // zero cv for atomic accumulation (d_out is poisoned before every call)
    hipMemsetAsync(cv, 0, (size_t)B_N*D_DIM*sizeof(float), stream);

    proj_kernel<<<dim3(B_N, 2), 256, 0, stream>>>(query, Wq_m, bq_m, Wq_c, bq_c,
                                                  Wk_m, bk_m, Wk_c, bk_c, r,
                                                  v_all, c_all);
    energy_kernel<<<dim3(B_N, 16), 256, 0, stream>>>(key, mask, v_all, c_all, e_mono, e_c);
    scan_kernel<<<B_N, 512, 0, stream>>>(e_mono, e_c, noise, aw_prev, alpha, beta);
    cv_part_kernel<<<dim3(B_N, 20), 256, 0, stream>>>(value, beta, cv);
}